// Round 2
// baseline (3737.732 us; speedup 1.0000x reference)
//
#include <hip/hip_runtime.h>

#define Bn 2
#define Nn 100000
#define DIM 128
#define En 600000
#define MTOT (Bn * Nn)   // 200000 nodes total (divisible by 16)

typedef __attribute__((ext_vector_type(8))) short bf16x8;
typedef __attribute__((ext_vector_type(4))) float f32x4;

__device__ __forceinline__ unsigned short f2bf(float f) {
    union { float f; unsigned u; } v; v.f = f;
    unsigned r = v.u + 0x7fffu + ((v.u >> 16) & 1u);   // RNE
    return (unsigned short)(r >> 16);
}
__device__ __forceinline__ float bf2f(unsigned u16) {
    union { unsigned u; float f; } v; v.u = u16 << 16; return v.f;
}

// ---------------- x -> bf16 ----------------
__global__ __launch_bounds__(256) void cvt_x_kernel(const float4* __restrict__ x,
                                                    ushort4* __restrict__ xbf) {
    int i = blockIdx.x * 256 + threadIdx.x;           // MTOT*128/4 = 6.4M exact
    float4 v = x[i];
    ushort4 o;
    o.x = f2bf(v.x); o.y = f2bf(v.y); o.z = f2bf(v.z); o.w = f2bf(v.w);
    xbf[i] = o;
}

// ---------------- [w;gw] -> bf16 (one relation) ----------------
__global__ __launch_bounds__(256) void cvt_w_kernel(const float* __restrict__ w,
                                                    const float* __restrict__ gw,
                                                    unsigned short* __restrict__ WBr) {
    int idx = blockIdx.x * 256 + threadIdx.x;         // 384*128 = 49152, 192 blocks
    float v = (idx < 128 * 128) ? w[idx] : gw[idx - 128 * 128];
    WBr[idx] = f2bf(v);
}

// ---------------- node transform: A, S(=sigmoid(omega)), M ----------------
// out[node][o] = sum_k Xbf[node][k] * WB[o][k],  o in [0,384)
__global__ __launch_bounds__(256) void transform_kernel(
    const short* __restrict__ Xbf,          // [MTOT][128]
    const short* __restrict__ WB,           // [384][128] = [w ; gw]
    const float* __restrict__ gb,           // [256]
    unsigned short* __restrict__ Abuf,      // [MTOT][128]
    unsigned short* __restrict__ Sbuf,      // [MTOT][128]
    unsigned short* __restrict__ Mbuf)      // [MTOT][128]
{
    const int tid  = threadIdx.x;
    const int wave = tid >> 6;
    const int lane = tid & 63;
    const int m = lane & 15;                 // node within tile / output col
    const int q = lane >> 4;                 // quad
    const size_t mbase = (size_t)blockIdx.x * 16;

    f32x4 acc[6];
#pragma unroll
    for (int t = 0; t < 6; ++t) acc[t] = (f32x4){0.f, 0.f, 0.f, 0.f};

#pragma unroll
    for (int c = 0; c < 4; ++c) {            // K chunks of 32
        bf16x8 a = *(const bf16x8*)(Xbf + (mbase + (size_t)m) * DIM + c * 32 + q * 8);
#pragma unroll
        for (int t = 0; t < 6; ++t) {
            int o = wave * 96 + t * 16 + m;
            bf16x8 b = *(const bf16x8*)(WB + (size_t)o * DIM + c * 32 + q * 8);
            acc[t] = __builtin_amdgcn_mfma_f32_16x16x32_bf16(a, b, acc[t], 0, 0, 0);
        }
    }

#pragma unroll
    for (int t = 0; t < 6; ++t) {
        int o = wave * 96 + t * 16 + m;      // 0..383
#pragma unroll
        for (int i = 0; i < 4; ++i) {
            size_t node = mbase + (size_t)(q * 4 + i);
            float v = acc[t][i];
            if (o < 128) {
                Abuf[node * DIM + o] = f2bf(v);
            } else if (o < 256) {
                float z = v + gb[o - 128];
                float s = 1.f / (1.f + __expf(-z));
                Sbuf[node * DIM + (o - 128)] = f2bf(s);
            } else {
                Mbuf[node * DIM + (o - 256)] = f2bf(v + gb[o - 128]);
            }
        }
    }
}

// ---------------- edge scatter: one wave per (edge, batch) ----------------
__global__ __launch_bounds__(256) void scatter_kernel(
    const unsigned short* __restrict__ Abuf,
    const unsigned short* __restrict__ Sbuf,
    const unsigned short* __restrict__ Mbuf,
    const int* __restrict__ edges,          // [2][E], int32
    float* __restrict__ out)                // [MTOT][128]
{
    int wid  = blockIdx.x * 4 + (threadIdx.x >> 6);   // 0 .. E*B-1 (exact)
    int lane = threadIdx.x & 63;
    int e = wid >> 1;
    int b = wid & 1;

    int src = edges[e];
    int dst = edges[En + e];

    size_t arow = ((size_t)b * Nn + (size_t)src) * DIM;
    size_t drow = ((size_t)b * Nn + (size_t)dst) * DIM;
    int k = lane * 2;

    unsigned av = *(const unsigned*)(Abuf + arow + k);
    unsigned sv = *(const unsigned*)(Sbuf + drow + k);
    unsigned mv = *(const unsigned*)(Mbuf + drow + k);

    float a0 = bf2f(av & 0xffffu), a1 = bf2f(av >> 16);
    float s0 = bf2f(sv & 0xffffu), s1 = bf2f(sv >> 16);
    float m0 = bf2f(mv & 0xffffu), m1 = bf2f(mv >> 16);

    float r0 = s0 * a0 + m0; r0 = r0 > 0.f ? r0 : 0.f;
    float r1 = s1 * a1 + m1; r1 = r1 > 0.f ? r1 : 0.f;

    unsafeAtomicAdd(out + drow + k,     r0);
    unsafeAtomicAdd(out + drow + k + 1, r1);
}

// ---------------- fallback (ws too small): direct per-edge compute ----------------
__global__ __launch_bounds__(128) void fallback_kernel(
    const float* __restrict__ x,
    const int* __restrict__ edges,
    const float* __restrict__ w,            // [128][128]
    const float* __restrict__ gw,           // [256][128]
    const float* __restrict__ gb,           // [256]
    float* __restrict__ out)
{
    __shared__ float xs[DIM], xd[DIM];
    int be = blockIdx.x;                     // 0 .. E*B-1
    int e = be >> 1, b = be & 1;
    int t = threadIdx.x;
    int src = edges[e], dst = edges[En + e];
    xs[t] = x[((size_t)b * Nn + src) * DIM + t];
    xd[t] = x[((size_t)b * Nn + dst) * DIM + t];
    __syncthreads();
    float ml = 0.f, om = gb[t], mu = gb[128 + t];
    for (int kk = 0; kk < DIM; ++kk) {
        float xsk = xs[kk], xdk = xd[kk];
        ml += w[t * DIM + kk] * xsk;
        om += gw[t * DIM + kk] * xdk;
        mu += gw[(128 + t) * DIM + kk] * xdk;
    }
    float s = 1.f / (1.f + __expf(-om));
    float msg = s * ml + mu;
    msg = msg > 0.f ? msg : 0.f;
    unsafeAtomicAdd(out + ((size_t)b * Nn + dst) * DIM + t, msg);
}

extern "C" void kernel_launch(void* const* d_in, const int* in_sizes, int n_in,
                              void* d_out, int out_size, void* d_ws, size_t ws_size,
                              hipStream_t stream) {
    const float* x    = (const float*)d_in[0];
    const int*   ed[3] = { (const int*)d_in[1],
                           (const int*)d_in[2],
                           (const int*)d_in[3] };
    const float* w[3]  = { (const float*)d_in[4], (const float*)d_in[7], (const float*)d_in[10] };
    const float* gw[3] = { (const float*)d_in[5], (const float*)d_in[8], (const float*)d_in[11] };
    const float* gb[3] = { (const float*)d_in[6], (const float*)d_in[9], (const float*)d_in[12] };
    float* out = (float*)d_out;

    hipMemsetAsync(d_out, 0, (size_t)MTOT * DIM * sizeof(float), stream);

    const size_t xbf_sz = (size_t)MTOT * DIM * 2;       // 51.2 MB
    const size_t wb_sz  = (size_t)3 * 384 * DIM * 2;    // 294 KB
    const size_t buf_sz = (size_t)MTOT * DIM * 2;       // 51.2 MB each
    const size_t need   = xbf_sz + wb_sz + 3 * buf_sz + 1024;

    if (ws_size >= need) {
        char* p = (char*)d_ws;
        short*          Xbf = (short*)p;              p += xbf_sz;
        unsigned short* WB  = (unsigned short*)p;     p += wb_sz;
        unsigned short* Ab  = (unsigned short*)p;     p += buf_sz;
        unsigned short* Sb  = (unsigned short*)p;     p += buf_sz;
        unsigned short* Mb  = (unsigned short*)p;

        cvt_x_kernel<<<(MTOT * DIM / 4) / 256, 256, 0, stream>>>((const float4*)x, (ushort4*)Xbf);
        for (int r = 0; r < 3; ++r)
            cvt_w_kernel<<<(384 * DIM) / 256, 256, 0, stream>>>(w[r], gw[r], WB + (size_t)r * 384 * DIM);

        for (int r = 0; r < 3; ++r) {
            transform_kernel<<<MTOT / 16, 256, 0, stream>>>(
                Xbf, (const short*)(WB + (size_t)r * 384 * DIM), gb[r], Ab, Sb, Mb);
            scatter_kernel<<<(En * Bn) / 4, 256, 0, stream>>>(Ab, Sb, Mb, ed[r], out);
        }
    } else {
        for (int r = 0; r < 3; ++r)
            fallback_kernel<<<En * Bn, 128, 0, stream>>>(x, ed[r], w[r], gw[r], gb[r], out);
    }
}

// Round 3
// 1670.281 us; speedup vs baseline: 2.2378x; 2.2378x over previous
//
#include <hip/hip_runtime.h>

#define Bn 2
#define Nn 100000
#define DIM 128
#define En 600000
#define MTOT (Bn * Nn)   // 200000 nodes total

typedef __attribute__((ext_vector_type(8))) short bf16x8;
typedef __attribute__((ext_vector_type(4))) float f32x4;

__device__ __forceinline__ unsigned short f2bf(float f) {
    union { float f; unsigned u; } v; v.f = f;
    unsigned r = v.u + 0x7fffu + ((v.u >> 16) & 1u);   // RNE
    return (unsigned short)(r >> 16);
}
__device__ __forceinline__ float bf2f(unsigned u16) {
    union { unsigned u; float f; } v; v.u = u16 << 16; return v.f;
}

// ---------------- x -> bf16 ----------------
__global__ __launch_bounds__(256) void cvt_x_kernel(const float4* __restrict__ x,
                                                    ushort4* __restrict__ xbf) {
    int i = blockIdx.x * 256 + threadIdx.x;           // MTOT*128/4 = 6.4M exact
    float4 v = x[i];
    ushort4 o;
    o.x = f2bf(v.x); o.y = f2bf(v.y); o.z = f2bf(v.z); o.w = f2bf(v.w);
    xbf[i] = o;
}

// ---------------- [w;gw] -> bf16 (one relation) ----------------
__global__ __launch_bounds__(256) void cvt_w_kernel(const float* __restrict__ w,
                                                    const float* __restrict__ gw,
                                                    unsigned short* __restrict__ WBr) {
    int idx = blockIdx.x * 256 + threadIdx.x;         // 384*128 = 49152
    float v = (idx < 128 * 128) ? w[idx] : gw[idx - 128 * 128];
    WBr[idx] = f2bf(v);
}

// ---------------- CSR build: count ----------------
__global__ __launch_bounds__(256) void count_kernel(
    const int* __restrict__ e0, const int* __restrict__ e1, const int* __restrict__ e2,
    int* __restrict__ counts)                         // [3][Nn]
{
    int idx = blockIdx.x * 256 + threadIdx.x;
    if (idx >= 3 * En) return;
    int r = (idx >= 2 * En) ? 2 : (idx >= En ? 1 : 0);
    int e = idx - r * En;
    const int* ed = (r == 0) ? e0 : (r == 1 ? e1 : e2);
    int dst = ed[En + e];
    atomicAdd(&counts[r * Nn + dst], 1);
}

// ---------------- CSR build: exclusive scan (one block per relation) -------
__global__ __launch_bounds__(256) void scan_kernel(
    const int* __restrict__ counts,                   // [3][Nn]
    int* __restrict__ offsets)                        // [3][Nn+1]
{
    const int r = blockIdx.x;
    const int* c = counts + (size_t)r * Nn;
    int* o = offsets + (size_t)r * (Nn + 1);
    const int t = threadIdx.x;
    const int CH = (Nn + 255) / 256;                  // 391
    const int base = t * CH;

    int s = 0;
    for (int i = 0; i < CH; ++i) {
        int idx = base + i;
        if (idx < Nn) s += c[idx];
    }
    __shared__ int tmp[256];
    tmp[t] = s; __syncthreads();
    for (int d = 1; d < 256; d <<= 1) {               // inclusive Hillis-Steele
        int v = (t >= d) ? tmp[t - d] : 0;
        __syncthreads();
        tmp[t] += v;
        __syncthreads();
    }
    int run = (t == 0) ? 0 : tmp[t - 1];
    for (int i = 0; i < CH; ++i) {
        int idx = base + i;
        if (idx < Nn) { o[idx] = run; run += c[idx]; }
    }
    if (t == 255) o[Nn] = tmp[255];                   // = En
}

// ---------------- CSR build: fill ----------------
__global__ __launch_bounds__(256) void fill_kernel(
    const int* __restrict__ e0, const int* __restrict__ e1, const int* __restrict__ e2,
    const int* __restrict__ offsets,                  // [3][Nn+1]
    int* __restrict__ cursor,                         // [3][Nn]
    int* __restrict__ records)                        // [3][En] -> src
{
    int idx = blockIdx.x * 256 + threadIdx.x;
    if (idx >= 3 * En) return;
    int r = (idx >= 2 * En) ? 2 : (idx >= En ? 1 : 0);
    int e = idx - r * En;
    const int* ed = (r == 0) ? e0 : (r == 1 ? e1 : e2);
    int src = ed[e];
    int dst = ed[En + e];
    int pos = atomicAdd(&cursor[r * Nn + dst], 1);
    records[(size_t)r * En + offsets[r * (Nn + 1) + dst] + pos] = src;
}

// ---------------- node transform: A, S(=sigmoid(omega)), M ----------------
__global__ __launch_bounds__(256) void transform_kernel(
    const short* __restrict__ Xbf,          // [MTOT][128]
    const short* __restrict__ WB,           // [384][128] = [w ; gw]
    const float* __restrict__ gb,           // [256]
    unsigned short* __restrict__ Abuf,
    unsigned short* __restrict__ Sbuf,
    unsigned short* __restrict__ Mbuf)
{
    const int tid  = threadIdx.x;
    const int wave = tid >> 6;
    const int lane = tid & 63;
    const int m = lane & 15;
    const int q = lane >> 4;
    const size_t mbase = (size_t)blockIdx.x * 16;

    f32x4 acc[6];
#pragma unroll
    for (int t = 0; t < 6; ++t) acc[t] = (f32x4){0.f, 0.f, 0.f, 0.f};

#pragma unroll
    for (int c = 0; c < 4; ++c) {
        bf16x8 a = *(const bf16x8*)(Xbf + (mbase + (size_t)m) * DIM + c * 32 + q * 8);
#pragma unroll
        for (int t = 0; t < 6; ++t) {
            int o = wave * 96 + t * 16 + m;
            bf16x8 b = *(const bf16x8*)(WB + (size_t)o * DIM + c * 32 + q * 8);
            acc[t] = __builtin_amdgcn_mfma_f32_16x16x32_bf16(a, b, acc[t], 0, 0, 0);
        }
    }

#pragma unroll
    for (int t = 0; t < 6; ++t) {
        int o = wave * 96 + t * 16 + m;
#pragma unroll
        for (int i = 0; i < 4; ++i) {
            size_t node = mbase + (size_t)(q * 4 + i);
            float v = acc[t][i];
            if (o < 128) {
                Abuf[node * DIM + o] = f2bf(v);
            } else if (o < 256) {
                float z = v + gb[o - 128];
                float s = 1.f / (1.f + __expf(-z));
                Sbuf[node * DIM + (o - 128)] = f2bf(s);
            } else {
                Mbuf[node * DIM + (o - 256)] = f2bf(v + gb[o - 128]);
            }
        }
    }
}

// ---------------- accumulate: one wave per (dst,b), no atomics -------------
template <int FIRST>
__global__ __launch_bounds__(256) void accum_kernel(
    const unsigned short* __restrict__ Abuf,
    const unsigned short* __restrict__ Sbuf,
    const unsigned short* __restrict__ Mbuf,
    const int* __restrict__ offsets,        // [Nn+1] (this relation)
    const int* __restrict__ records,        // [En]   (this relation)
    float* __restrict__ out)                // [MTOT][128]
{
    int wid  = blockIdx.x * 4 + (threadIdx.x >> 6);   // 0 .. 2*Nn-1 (exact)
    int lane = threadIdx.x & 63;
    int b = wid & 1;
    int dst = wid >> 1;

    int beg = offsets[dst];
    int end = offsets[dst + 1];
    if (!FIRST && beg == end) return;

    size_t drow = ((size_t)b * Nn + (size_t)dst) * DIM;
    int k = lane * 2;

    unsigned sv = *(const unsigned*)(Sbuf + drow + k);
    unsigned mv = *(const unsigned*)(Mbuf + drow + k);
    float s0 = bf2f(sv & 0xffffu), s1 = bf2f(sv >> 16);
    float m0 = bf2f(mv & 0xffffu), m1 = bf2f(mv >> 16);

    float acc0 = 0.f, acc1 = 0.f;
    for (int i = beg; i < end; ++i) {
        int src = records[i];
        unsigned av = *(const unsigned*)(Abuf + ((size_t)b * Nn + src) * DIM + k);
        float a0 = bf2f(av & 0xffffu), a1 = bf2f(av >> 16);
        float r0 = s0 * a0 + m0; r0 = r0 > 0.f ? r0 : 0.f;
        float r1 = s1 * a1 + m1; r1 = r1 > 0.f ? r1 : 0.f;
        acc0 += r0; acc1 += r1;
    }

    float2* op = (float2*)(out + drow + k);
    if (FIRST) {
        *op = make_float2(acc0, acc1);
    } else {
        float2 v = *op;
        v.x += acc0; v.y += acc1;
        *op = v;
    }
}

// ---------------- fallback (ws too small): direct per-edge compute ---------
__global__ __launch_bounds__(128) void fallback_kernel(
    const float* __restrict__ x,
    const int* __restrict__ edges,
    const float* __restrict__ w,
    const float* __restrict__ gw,
    const float* __restrict__ gb,
    float* __restrict__ out)
{
    __shared__ float xs[DIM], xd[DIM];
    int be = blockIdx.x;
    int e = be >> 1, b = be & 1;
    int t = threadIdx.x;
    int src = edges[e], dst = edges[En + e];
    xs[t] = x[((size_t)b * Nn + src) * DIM + t];
    xd[t] = x[((size_t)b * Nn + dst) * DIM + t];
    __syncthreads();
    float ml = 0.f, om = gb[t], mu = gb[128 + t];
    for (int kk = 0; kk < DIM; ++kk) {
        float xsk = xs[kk], xdk = xd[kk];
        ml += w[t * DIM + kk] * xsk;
        om += gw[t * DIM + kk] * xdk;
        mu += gw[(128 + t) * DIM + kk] * xdk;
    }
    float s = 1.f / (1.f + __expf(-om));
    float msg = s * ml + mu;
    msg = msg > 0.f ? msg : 0.f;
    unsafeAtomicAdd(out + ((size_t)b * Nn + dst) * DIM + t, msg);
}

extern "C" void kernel_launch(void* const* d_in, const int* in_sizes, int n_in,
                              void* d_out, int out_size, void* d_ws, size_t ws_size,
                              hipStream_t stream) {
    const float* x    = (const float*)d_in[0];
    const int*   ed[3] = { (const int*)d_in[1],
                           (const int*)d_in[2],
                           (const int*)d_in[3] };
    const float* w[3]  = { (const float*)d_in[4], (const float*)d_in[7], (const float*)d_in[10] };
    const float* gw[3] = { (const float*)d_in[5], (const float*)d_in[8], (const float*)d_in[11] };
    const float* gb[3] = { (const float*)d_in[6], (const float*)d_in[9], (const float*)d_in[12] };
    float* out = (float*)d_out;

    const size_t xbf_sz  = (size_t)MTOT * DIM * 2;        // 51.2 MB
    const size_t wb_sz   = (size_t)3 * 384 * DIM * 2;     // 294 KB
    const size_t buf_sz  = (size_t)MTOT * DIM * 2;        // 51.2 MB each
    const size_t cnt_sz  = (size_t)3 * Nn * 4;            // counts  1.2 MB
    const size_t cur_sz  = (size_t)3 * Nn * 4;            // cursor  1.2 MB
    const size_t off_sz  = (size_t)3 * (Nn + 1) * 4;      // offsets 1.2 MB
    const size_t rec_sz  = (size_t)3 * En * 4;            // records 7.2 MB
    const size_t need    = xbf_sz + wb_sz + 3 * buf_sz + cnt_sz + cur_sz + off_sz + rec_sz + 1024;

    if (ws_size >= need) {
        char* p = (char*)d_ws;
        short*          Xbf = (short*)p;              p += xbf_sz;
        unsigned short* WB  = (unsigned short*)p;     p += wb_sz;
        unsigned short* Ab  = (unsigned short*)p;     p += buf_sz;
        unsigned short* Sb  = (unsigned short*)p;     p += buf_sz;
        unsigned short* Mb  = (unsigned short*)p;     p += buf_sz;
        int*            counts  = (int*)p;            p += cnt_sz;
        int*            cursor  = (int*)p;            p += cur_sz;
        int*            offsets = (int*)p;            p += off_sz;
        int*            records = (int*)p;

        // zero counts+cursor (contiguous)
        hipMemsetAsync(counts, 0, cnt_sz + cur_sz, stream);

        cvt_x_kernel<<<(MTOT * DIM / 4) / 256, 256, 0, stream>>>((const float4*)x, (ushort4*)Xbf);
        for (int r = 0; r < 3; ++r)
            cvt_w_kernel<<<(384 * DIM) / 256, 256, 0, stream>>>(w[r], gw[r], WB + (size_t)r * 384 * DIM);

        // CSR build (independent of transforms)
        count_kernel<<<(3 * En + 255) / 256, 256, 0, stream>>>(ed[0], ed[1], ed[2], counts);
        scan_kernel<<<3, 256, 0, stream>>>(counts, offsets);
        fill_kernel<<<(3 * En + 255) / 256, 256, 0, stream>>>(ed[0], ed[1], ed[2], offsets, cursor, records);

        for (int r = 0; r < 3; ++r) {
            transform_kernel<<<MTOT / 16, 256, 0, stream>>>(
                Xbf, (const short*)(WB + (size_t)r * 384 * DIM), gb[r], Ab, Sb, Mb);
            const int* offs = offsets + (size_t)r * (Nn + 1);
            const int* recs = records + (size_t)r * En;
            if (r == 0)
                accum_kernel<1><<<(2 * Nn) / 4, 256, 0, stream>>>(Ab, Sb, Mb, offs, recs, out);
            else
                accum_kernel<0><<<(2 * Nn) / 4, 256, 0, stream>>>(Ab, Sb, Mb, offs, recs, out);
        }
    } else {
        hipMemsetAsync(d_out, 0, (size_t)MTOT * DIM * sizeof(float), stream);
        for (int r = 0; r < 3; ++r)
            fallback_kernel<<<En * Bn, 128, 0, stream>>>(x, ed[r], w[r], gw[r], gb[r], out);
    }
}

// Round 4
// 1495.869 us; speedup vs baseline: 2.4987x; 1.1166x over previous
//
#include <hip/hip_runtime.h>

#define Bn 2
#define Nn 100000
#define DIM 128
#define En 600000
#define MTOT (Bn * Nn)   // 200000 nodes total

typedef __attribute__((ext_vector_type(8))) short bf16x8;
typedef __attribute__((ext_vector_type(4))) float f32x4;

__device__ __forceinline__ unsigned short f2bf(float f) {
    union { float f; unsigned u; } v; v.f = f;
    unsigned r = v.u + 0x7fffu + ((v.u >> 16) & 1u);   // RNE
    return (unsigned short)(r >> 16);
}
__device__ __forceinline__ float bf2f(unsigned u16) {
    union { unsigned u; float f; } v; v.u = u16 << 16; return v.f;
}

// ---------------- x -> bf16 ----------------
__global__ __launch_bounds__(256) void cvt_x_kernel(const float4* __restrict__ x,
                                                    ushort4* __restrict__ xbf) {
    int i = blockIdx.x * 256 + threadIdx.x;           // MTOT*128/4 = 6.4M exact
    float4 v = x[i];
    ushort4 o;
    o.x = f2bf(v.x); o.y = f2bf(v.y); o.z = f2bf(v.z); o.w = f2bf(v.w);
    xbf[i] = o;
}

// ---------------- [w;gw] -> bf16 (all 3 relations, one launch) -------------
__global__ __launch_bounds__(256) void cvt_w_kernel(
    const float* __restrict__ w0,  const float* __restrict__ gw0,
    const float* __restrict__ w1,  const float* __restrict__ gw1,
    const float* __restrict__ w2,  const float* __restrict__ gw2,
    unsigned short* __restrict__ WB)                  // [3][384][128]
{
    int idx = blockIdx.x * 256 + threadIdx.x;         // 3*49152
    int r = idx / 49152;
    int j = idx - r * 49152;
    const float* w  = (r == 0) ? w0  : (r == 1 ? w1  : w2);
    const float* gw = (r == 0) ? gw0 : (r == 1 ? gw1 : gw2);
    float v = (j < 128 * 128) ? w[j] : gw[j - 128 * 128];
    WB[idx] = f2bf(v);
}

// ---------------- CSR build: count ----------------
__global__ __launch_bounds__(256) void count_kernel(
    const int* __restrict__ e0, const int* __restrict__ e1, const int* __restrict__ e2,
    int* __restrict__ counts)                         // [3][Nn]
{
    int idx = blockIdx.x * 256 + threadIdx.x;
    if (idx >= 3 * En) return;
    int r = (idx >= 2 * En) ? 2 : (idx >= En ? 1 : 0);
    int e = idx - r * En;
    const int* ed = (r == 0) ? e0 : (r == 1 ? e1 : e2);
    int dst = ed[En + e];
    atomicAdd(&counts[r * Nn + dst], 1);
}

// ---------------- bucket allocator: wave-aggregated, no scan ---------------
// One wave handles 64 consecutive dsts of one relation; lane63 grabs a base
// from the per-relation cursor, lanes get base + in-wave exclusive prefix.
#define WPR 1563   // waves per relation = ceil(Nn/64)
__global__ __launch_bounds__(256) void alloc_kernel(
    const int* __restrict__ counts,                   // [3][Nn]
    int* __restrict__ starts,                         // [3][Nn]
    int* __restrict__ gcursor)                        // [3]
{
    int wid  = blockIdx.x * 4 + (threadIdx.x >> 6);
    int lane = threadIdx.x & 63;
    int r = wid / WPR;
    if (r >= 3) return;                               // whole wave exits
    int dst = (wid - r * WPR) * 64 + lane;
    int c = (dst < Nn) ? counts[r * Nn + dst] : 0;

    int inc = c;                                      // inclusive prefix
#pragma unroll
    for (int d = 1; d < 64; d <<= 1) {
        int v = __shfl_up(inc, d);
        if (lane >= d) inc += v;
    }
    int total = __shfl(inc, 63);
    int base = 0;
    if (lane == 63) base = atomicAdd(&gcursor[r], total);
    base = __shfl(base, 63);

    if (dst < Nn) starts[r * Nn + dst] = base + inc - c;
}

// ---------------- CSR build: fill ----------------
__global__ __launch_bounds__(256) void fill_kernel(
    const int* __restrict__ e0, const int* __restrict__ e1, const int* __restrict__ e2,
    const int* __restrict__ starts,                   // [3][Nn]
    int* __restrict__ cursor,                         // [3][Nn]
    int* __restrict__ records)                        // [3][En] -> src
{
    int idx = blockIdx.x * 256 + threadIdx.x;
    if (idx >= 3 * En) return;
    int r = (idx >= 2 * En) ? 2 : (idx >= En ? 1 : 0);
    int e = idx - r * En;
    const int* ed = (r == 0) ? e0 : (r == 1 ? e1 : e2);
    int src = ed[e];
    int dst = ed[En + e];
    int pos = atomicAdd(&cursor[r * Nn + dst], 1);
    records[(size_t)r * En + starts[r * Nn + dst] + pos] = src;
}

// ---------------- node transform: A, S(=sigmoid(omega)), M ----------------
__global__ __launch_bounds__(256) void transform_kernel(
    const short* __restrict__ Xbf,          // [MTOT][128]
    const short* __restrict__ WB,           // [384][128] = [w ; gw]
    const float* __restrict__ gb,           // [256]
    unsigned short* __restrict__ Abuf,
    unsigned short* __restrict__ Sbuf,
    unsigned short* __restrict__ Mbuf)
{
    const int tid  = threadIdx.x;
    const int wave = tid >> 6;
    const int lane = tid & 63;
    const int m = lane & 15;
    const int q = lane >> 4;
    const size_t mbase = (size_t)blockIdx.x * 16;

    f32x4 acc[6];
#pragma unroll
    for (int t = 0; t < 6; ++t) acc[t] = (f32x4){0.f, 0.f, 0.f, 0.f};

#pragma unroll
    for (int c = 0; c < 4; ++c) {
        bf16x8 a = *(const bf16x8*)(Xbf + (mbase + (size_t)m) * DIM + c * 32 + q * 8);
#pragma unroll
        for (int t = 0; t < 6; ++t) {
            int o = wave * 96 + t * 16 + m;
            bf16x8 b = *(const bf16x8*)(WB + (size_t)o * DIM + c * 32 + q * 8);
            acc[t] = __builtin_amdgcn_mfma_f32_16x16x32_bf16(a, b, acc[t], 0, 0, 0);
        }
    }

#pragma unroll
    for (int t = 0; t < 6; ++t) {
        int o = wave * 96 + t * 16 + m;
#pragma unroll
        for (int i = 0; i < 4; ++i) {
            size_t node = mbase + (size_t)(q * 4 + i);
            float v = acc[t][i];
            if (o < 128) {
                Abuf[node * DIM + o] = f2bf(v);
            } else if (o < 256) {
                float z = v + gb[o - 128];
                float s = 1.f / (1.f + __expf(-z));
                Sbuf[node * DIM + (o - 128)] = f2bf(s);
            } else {
                Mbuf[node * DIM + (o - 256)] = f2bf(v + gb[o - 128]);
            }
        }
    }
}

// ---------------- accumulate: one wave per (dst,b), no atomics -------------
template <int FIRST>
__global__ __launch_bounds__(256) void accum_kernel(
    const unsigned short* __restrict__ Abuf,
    const unsigned short* __restrict__ Sbuf,
    const unsigned short* __restrict__ Mbuf,
    const int* __restrict__ starts,         // [Nn] (this relation)
    const int* __restrict__ counts,         // [Nn] (this relation)
    const int* __restrict__ records,        // [En] (this relation)
    float* __restrict__ out)                // [MTOT][128]
{
    int wid  = blockIdx.x * 4 + (threadIdx.x >> 6);   // 0 .. 2*Nn-1 (exact)
    int lane = threadIdx.x & 63;
    int b = wid & 1;
    int dst = wid >> 1;

    int cnt = counts[dst];
    if (!FIRST && cnt == 0) return;
    int beg = starts[dst];
    int end = beg + cnt;

    size_t drow = ((size_t)b * Nn + (size_t)dst) * DIM;
    int k = lane * 2;

    unsigned sv = *(const unsigned*)(Sbuf + drow + k);
    unsigned mv = *(const unsigned*)(Mbuf + drow + k);
    float s0 = bf2f(sv & 0xffffu), s1 = bf2f(sv >> 16);
    float m0 = bf2f(mv & 0xffffu), m1 = bf2f(mv >> 16);

    float acc0 = 0.f, acc1 = 0.f;
    for (int i = beg; i < end; ++i) {
        int src = records[i];
        unsigned av = *(const unsigned*)(Abuf + ((size_t)b * Nn + src) * DIM + k);
        float a0 = bf2f(av & 0xffffu), a1 = bf2f(av >> 16);
        float r0 = s0 * a0 + m0; r0 = r0 > 0.f ? r0 : 0.f;
        float r1 = s1 * a1 + m1; r1 = r1 > 0.f ? r1 : 0.f;
        acc0 += r0; acc1 += r1;
    }

    float2* op = (float2*)(out + drow + k);
    if (FIRST) {
        *op = make_float2(acc0, acc1);
    } else {
        float2 v = *op;
        v.x += acc0; v.y += acc1;
        *op = v;
    }
}

// ---------------- fallback (ws too small): direct per-edge compute ---------
__global__ __launch_bounds__(128) void fallback_kernel(
    const float* __restrict__ x,
    const int* __restrict__ edges,
    const float* __restrict__ w,
    const float* __restrict__ gw,
    const float* __restrict__ gb,
    float* __restrict__ out)
{
    __shared__ float xs[DIM], xd[DIM];
    int be = blockIdx.x;
    int e = be >> 1, b = be & 1;
    int t = threadIdx.x;
    int src = edges[e], dst = edges[En + e];
    xs[t] = x[((size_t)b * Nn + src) * DIM + t];
    xd[t] = x[((size_t)b * Nn + dst) * DIM + t];
    __syncthreads();
    float ml = 0.f, om = gb[t], mu = gb[128 + t];
    for (int kk = 0; kk < DIM; ++kk) {
        float xsk = xs[kk], xdk = xd[kk];
        ml += w[t * DIM + kk] * xsk;
        om += gw[t * DIM + kk] * xdk;
        mu += gw[(128 + t) * DIM + kk] * xdk;
    }
    float s = 1.f / (1.f + __expf(-om));
    float msg = s * ml + mu;
    msg = msg > 0.f ? msg : 0.f;
    unsafeAtomicAdd(out + ((size_t)b * Nn + dst) * DIM + t, msg);
}

extern "C" void kernel_launch(void* const* d_in, const int* in_sizes, int n_in,
                              void* d_out, int out_size, void* d_ws, size_t ws_size,
                              hipStream_t stream) {
    const float* x    = (const float*)d_in[0];
    const int*   ed[3] = { (const int*)d_in[1],
                           (const int*)d_in[2],
                           (const int*)d_in[3] };
    const float* w[3]  = { (const float*)d_in[4], (const float*)d_in[7], (const float*)d_in[10] };
    const float* gw[3] = { (const float*)d_in[5], (const float*)d_in[8], (const float*)d_in[11] };
    const float* gb[3] = { (const float*)d_in[6], (const float*)d_in[9], (const float*)d_in[12] };
    float* out = (float*)d_out;

    const size_t xbf_sz  = (size_t)MTOT * DIM * 2;        // 51.2 MB
    const size_t wb_sz   = (size_t)3 * 384 * DIM * 2;     // 294 KB
    const size_t buf_sz  = (size_t)MTOT * DIM * 2;        // 51.2 MB each
    const size_t cnt_sz  = (size_t)3 * Nn * 4;            // counts  1.2 MB
    const size_t cur_sz  = (size_t)3 * Nn * 4;            // cursor  1.2 MB
    const size_t gcu_sz  = 64;                            // 3 cursors, padded
    const size_t sta_sz  = (size_t)3 * Nn * 4;            // starts  1.2 MB
    const size_t rec_sz  = (size_t)3 * En * 4;            // records 7.2 MB
    const size_t need    = xbf_sz + wb_sz + 3 * buf_sz + cnt_sz + cur_sz + gcu_sz + sta_sz + rec_sz + 1024;

    if (ws_size >= need) {
        char* p = (char*)d_ws;
        short*          Xbf = (short*)p;              p += xbf_sz;
        unsigned short* WB  = (unsigned short*)p;     p += wb_sz;
        unsigned short* Ab  = (unsigned short*)p;     p += buf_sz;
        unsigned short* Sb  = (unsigned short*)p;     p += buf_sz;
        unsigned short* Mb  = (unsigned short*)p;     p += buf_sz;
        int*            counts  = (int*)p;            p += cnt_sz;
        int*            cursor  = (int*)p;            p += cur_sz;
        int*            gcursor = (int*)p;            p += gcu_sz;
        int*            starts  = (int*)p;            p += sta_sz;
        int*            records = (int*)p;

        // zero counts + cursor + gcursor (contiguous)
        hipMemsetAsync(counts, 0, cnt_sz + cur_sz + gcu_sz, stream);

        cvt_x_kernel<<<(MTOT * DIM / 4) / 256, 256, 0, stream>>>((const float4*)x, (ushort4*)Xbf);
        cvt_w_kernel<<<(3 * 384 * DIM) / 256, 256, 0, stream>>>(
            w[0], gw[0], w[1], gw[1], w[2], gw[2], WB);

        // CSR build (independent of transforms)
        count_kernel<<<(3 * En + 255) / 256, 256, 0, stream>>>(ed[0], ed[1], ed[2], counts);
        alloc_kernel<<<(3 * WPR + 3) / 4, 256, 0, stream>>>(counts, starts, gcursor);
        fill_kernel<<<(3 * En + 255) / 256, 256, 0, stream>>>(ed[0], ed[1], ed[2], starts, cursor, records);

        for (int r = 0; r < 3; ++r) {
            transform_kernel<<<MTOT / 16, 256, 0, stream>>>(
                Xbf, (const short*)(WB + (size_t)r * 384 * DIM), gb[r], Ab, Sb, Mb);
            const int* sta = starts + (size_t)r * Nn;
            const int* cnt = counts + (size_t)r * Nn;
            const int* rec = records + (size_t)r * En;
            if (r == 0)
                accum_kernel<1><<<(2 * Nn) / 4, 256, 0, stream>>>(Ab, Sb, Mb, sta, cnt, rec, out);
            else
                accum_kernel<0><<<(2 * Nn) / 4, 256, 0, stream>>>(Ab, Sb, Mb, sta, cnt, rec, out);
        }
    } else {
        hipMemsetAsync(d_out, 0, (size_t)MTOT * DIM * sizeof(float), stream);
        for (int r = 0; r < 3; ++r)
            fallback_kernel<<<En * Bn, 128, 0, stream>>>(x, ed[r], w[r], gw[r], gb[r], out);
    }
}